// Round 1
// baseline (78.178 us; speedup 1.0000x reference)
//
#include <hip/hip_runtime.h>

// KAN neuron, Chebyshev basis, degree 8 (fixed).
// y[b] = sum_d sum_k c[d*9+k] * T_k(x[b,d]);  x:(16384,512) f32, c:(4608,) f32.
//
// Memory-bound: 33.6 MB of x per call -> ~5.3 us floor at 6.3 TB/s.
// Structure: 1 wave per row; lane i owns dims {4i..4i+3} and {256+4i..256+4i+3}
// -> two coalesced float4 loads per row (16 B/lane). Coefficients (72 floats
// per lane) hoisted into registers before the row loop (no LDS, no reload).

#define DIM 512
#define DEGP1 9

__global__ void kan_cheb_kernel(const float* __restrict__ x,
                                const float* __restrict__ coeff,
                                float* __restrict__ out,
                                int batch) {
    const int lane = threadIdx.x & 63;
    const int wave_in_block = threadIdx.x >> 6;
    const int waves_per_block = blockDim.x >> 6;
    const int gwave = blockIdx.x * waves_per_block + wave_in_block;
    const int nwaves = gridDim.x * waves_per_block;

    const int d0 = 4 * lane;        // first float4 group of dims
    const int d1 = 256 + 4 * lane;  // second float4 group of dims

    // Hoist this lane's 8 dims x 9 coefficients into registers.
    // Scattered reads, but only 18 KB total -> L1-resident, once per thread.
    float c[8][DEGP1];
#pragma unroll
    for (int j = 0; j < 4; ++j) {
#pragma unroll
        for (int k = 0; k < DEGP1; ++k) {
            c[j][k]     = coeff[(d0 + j) * DEGP1 + k];
            c[4 + j][k] = coeff[(d1 + j) * DEGP1 + k];
        }
    }

    for (int row = gwave; row < batch; row += nwaves) {
        const size_t base = (size_t)row * DIM;
        const float4 xa = *(const float4*)(x + base + d0);
        const float4 xb = *(const float4*)(x + base + d1);
        const float xs[8] = {xa.x, xa.y, xa.z, xa.w, xb.x, xb.y, xb.z, xb.w};

        float acc = 0.0f;
#pragma unroll
        for (int j = 0; j < 8; ++j) {
            const float xv = xs[j];
            // T_0 = 1, T_1 = x; acc_d = c0 + c1*x
            float t0 = 1.0f;
            float t1 = xv;
            float a  = fmaf(c[j][1], xv, c[j][0]);
            const float x2 = xv + xv;
#pragma unroll
            for (int k = 2; k < DEGP1; ++k) {
                const float t2 = fmaf(x2, t1, -t0);  // T_k = 2x*T_{k-1} - T_{k-2}
                a  = fmaf(c[j][k], t2, a);
                t0 = t1;
                t1 = t2;
            }
            acc += a;
        }

        // Wave-level sum across 64 lanes.
#pragma unroll
        for (int off = 32; off > 0; off >>= 1)
            acc += __shfl_down(acc, off, 64);

        if (lane == 0) out[row] = acc;
    }
}

extern "C" void kernel_launch(void* const* d_in, const int* in_sizes, int n_in,
                              void* d_out, int out_size, void* d_ws, size_t ws_size,
                              hipStream_t stream) {
    const float* x     = (const float*)d_in[0];
    const float* coeff = (const float*)d_in[1];
    // d_in[2] is degree == 8, fixed; hard-coded in the kernel.
    float* out = (float*)d_out;

    const int batch = in_sizes[0] / DIM;  // 16384

    // 1024 blocks x 256 threads = 4096 waves -> 4 rows per wave (grid-stride).
    dim3 grid(1024), block(256);
    hipLaunchKernelGGL(kan_cheb_kernel, grid, block, 0, stream,
                       x, coeff, out, batch);
}

// Round 2
// 75.464 us; speedup vs baseline: 1.0360x; 1.0360x over previous
//
#include <hip/hip_runtime.h>

// KAN neuron, Chebyshev basis, degree 8 (fixed).
// y[b] = sum_d sum_k c[d*9+k] * T_k(x[b,d]);  x:(16384,512) f32, c:(4608,) f32.
//
// Memory-bound: 33.6 MB of x per call -> ~5.3 us floor at 6.3 TB/s.
// R1 lesson: per-lane register hoist of coeffs was a 144B-stride gather
// (72 loads x 64 cache lines each) -> ~31 us of TA occupancy. Fix: stage
// coeffs via LDS — coalesced float4 block fill, transposed to cs[k][d] so the
// per-wave register hoist is 18 conflict-free ds_read_b128.

#define DIM 512
#define DEGP1 9
#define NCOEFF (DIM * DEGP1)      // 4608
#define NCOEFF4 (NCOEFF / 4)      // 1152

__global__ void kan_cheb_kernel(const float* __restrict__ x,
                                const float* __restrict__ coeff,
                                float* __restrict__ out,
                                int batch) {
    // LDS: coeffs transposed to [k][d] so lanes read float4 of 4 consecutive
    // dims for fixed k: byte addr = 2048*k + 16*lane -> conflict-free b128.
    __shared__ float cs[DEGP1 * DIM];  // 18 KB

    const int tid = threadIdx.x;

    // ---- Block-cooperative coalesced fill + transpose ----
    const float4* coeff4 = (const float4*)coeff;
    for (int idx = tid; idx < NCOEFF4; idx += 256) {
        const float4 v = coeff4[idx];
        const int g = 4 * idx;
        const float vv[4] = {v.x, v.y, v.z, v.w};
#pragma unroll
        for (int m = 0; m < 4; ++m) {
            const int gg = g + m;
            const int d = gg / DEGP1;   // compile-time magic-mul by 9
            const int k = gg - d * DEGP1;
            cs[k * DIM + d] = vv[m];
        }
    }
    __syncthreads();

    const int lane = tid & 63;
    const int wave_in_block = tid >> 6;
    const int waves_per_block = blockDim.x >> 6;
    const int gwave = blockIdx.x * waves_per_block + wave_in_block;
    const int nwaves = gridDim.x * waves_per_block;

    const int d0 = 4 * lane;        // first float4 group of dims
    const int d1 = 256 + 4 * lane;  // second float4 group of dims

    // ---- Per-wave register hoist: 18 conflict-free ds_read_b128 ----
    float c[8][DEGP1];
#pragma unroll
    for (int k = 0; k < DEGP1; ++k) {
        const float4 va = *(const float4*)&cs[k * DIM + d0];
        const float4 vb = *(const float4*)&cs[k * DIM + d1];
        c[0][k] = va.x; c[1][k] = va.y; c[2][k] = va.z; c[3][k] = va.w;
        c[4][k] = vb.x; c[5][k] = vb.y; c[6][k] = vb.z; c[7][k] = vb.w;
    }

    // ---- Streaming row loop ----
    for (int row = gwave; row < batch; row += nwaves) {
        const size_t base = (size_t)row * DIM;
        const float4 xa = *(const float4*)(x + base + d0);
        const float4 xb = *(const float4*)(x + base + d1);
        const float xs[8] = {xa.x, xa.y, xa.z, xa.w, xb.x, xb.y, xb.z, xb.w};

        float acc = 0.0f;
#pragma unroll
        for (int j = 0; j < 8; ++j) {
            const float xv = xs[j];
            float t0 = 1.0f;
            float t1 = xv;
            float a  = fmaf(c[j][1], xv, c[j][0]);
            const float x2 = xv + xv;
#pragma unroll
            for (int k = 2; k < DEGP1; ++k) {
                const float t2 = fmaf(x2, t1, -t0);  // T_k = 2x*T_{k-1} - T_{k-2}
                a  = fmaf(c[j][k], t2, a);
                t0 = t1;
                t1 = t2;
            }
            acc += a;
        }

        // Wave-level sum across 64 lanes.
#pragma unroll
        for (int off = 32; off > 0; off >>= 1)
            acc += __shfl_down(acc, off, 64);

        if (lane == 0) out[row] = acc;
    }
}

extern "C" void kernel_launch(void* const* d_in, const int* in_sizes, int n_in,
                              void* d_out, int out_size, void* d_ws, size_t ws_size,
                              hipStream_t stream) {
    const float* x     = (const float*)d_in[0];
    const float* coeff = (const float*)d_in[1];
    // d_in[2] is degree == 8, fixed; hard-coded in the kernel.
    float* out = (float*)d_out;

    const int batch = in_sizes[0] / DIM;  // 16384

    // 1024 blocks x 256 threads = 4096 waves -> 4 rows per wave (grid-stride).
    dim3 grid(1024), block(256);
    hipLaunchKernelGGL(kan_cheb_kernel, grid, block, 0, stream,
                       x, coeff, out, batch);
}